// Round 2
// baseline (12.868 us; speedup 1.0000x reference)
//
#include <hip/hip_runtime.h>

// SoftmaxEncoder_20160576488053 — round 2
//
// The reference's transformer/cot loop only APPENDS rows to H; the readout
// uses H[:, :11, :], which is just the initial embedding of rows 0..10.
// Full op:  out[b,p,c] = (z[b,p,:] @ W_in + b_in) @ W_out[:, 32+c] + b_out[32+c]
// where z has only 64 nonzero entries: [ys row | (p<5)? xs row : 0].
//
// Round-2 refactor: precombine Wc = W_in[0:64,:] @ W_out[:,32:128]  (64x96)
//                   bc = b_in @ W_out[:,32:128] + b_out[32:128]     (96)
// into d_ws (kernel A), then out = z[0:64] @ Wc + bc (kernel B).
// Halves per-output FMA work, removes the mid-block barrier, and both
// kernels use 4 accumulators to break the dependent-FMA chain.
//
// Inputs: 0 xs, 1 ys, 2 head_mask, 3 read_in_w, 4 read_in_b, 5..13 unused,
// 14 read_out_w, 15 read_out_b. Output: (64, 11, 96) float32.

#define BB    64
#define NPT   11
#define DD    32
#define EE    128
#define CC    96     // output channels = E - d
#define ZZ    64     // active z columns
#define HALFN 5

// Kernel A: 65 blocks x 128 threads.
// Blocks 0..63: Wc[e, c] = sum_f W_in[e, f] * W_out[f, 32+c]
// Block 64:     bc[c]    = b_out[32+c] + sum_f b_in[f] * W_out[f, 32+c]
__global__ __launch_bounds__(128) void precombine_kernel(
    const float* __restrict__ w_in,   // (128,128)
    const float* __restrict__ b_in,   // (128)
    const float* __restrict__ w_out,  // (128,128)
    const float* __restrict__ b_out,  // (128)
    float* __restrict__ wc,           // (64,96) in d_ws
    float* __restrict__ bc)           // (96)    in d_ws
{
    const int e = blockIdx.x;
    const int c = threadIdx.x;
    if (c >= CC) return;

    const float* __restrict__ row = (e < ZZ) ? (w_in + e * EE) : b_in;

    float a0 = 0.f, a1 = 0.f, a2 = 0.f, a3 = 0.f;
    #pragma unroll 4
    for (int f = 0; f < EE; f += 4) {
        a0 = fmaf(row[f + 0], w_out[(f + 0) * EE + DD + c], a0);
        a1 = fmaf(row[f + 1], w_out[(f + 1) * EE + DD + c], a1);
        a2 = fmaf(row[f + 2], w_out[(f + 2) * EE + DD + c], a2);
        a3 = fmaf(row[f + 3], w_out[(f + 3) * EE + DD + c], a3);
    }
    float r = (a0 + a1) + (a2 + a3);
    if (e < ZZ) wc[e * CC + c] = r;
    else        bc[c] = r + b_out[DD + c];
}

// Kernel B: 704 blocks x 128 threads, one (b,p) row each.
__global__ __launch_bounds__(128) void readout_kernel(
    const float* __restrict__ xs,   // (64,256,32)
    const float* __restrict__ ys,   // (64,256,32)
    const float* __restrict__ wc,   // (64,96)
    const float* __restrict__ bc,   // (96)
    float* __restrict__ out)        // (64,11,96)
{
    const int b = blockIdx.x / NPT;
    const int p = blockIdx.x % NPT;
    const int t = threadIdx.x;

    __shared__ float z[ZZ];
    if (t < DD) {
        z[t] = ys[(b * 256 + p) * DD + t];
    } else if (t < ZZ) {
        z[t] = (p < HALFN) ? xs[(b * 256 + p) * DD + (t - DD)] : 0.0f;
    }
    __syncthreads();

    if (t < CC) {
        float a0 = bc[t], a1 = 0.f, a2 = 0.f, a3 = 0.f;
        #pragma unroll 4
        for (int e = 0; e < ZZ; e += 4) {
            a0 = fmaf(z[e + 0], wc[(e + 0) * CC + t], a0);  // z broadcast, wc coalesced
            a1 = fmaf(z[e + 1], wc[(e + 1) * CC + t], a1);
            a2 = fmaf(z[e + 2], wc[(e + 2) * CC + t], a2);
            a3 = fmaf(z[e + 3], wc[(e + 3) * CC + t], a3);
        }
        out[(b * NPT + p) * CC + t] = (a0 + a1) + (a2 + a3);
    }
}

extern "C" void kernel_launch(void* const* d_in, const int* in_sizes, int n_in,
                              void* d_out, int out_size, void* d_ws, size_t ws_size,
                              hipStream_t stream) {
    const float* xs    = (const float*)d_in[0];
    const float* ys    = (const float*)d_in[1];
    const float* w_in  = (const float*)d_in[3];
    const float* b_in  = (const float*)d_in[4];
    const float* w_out = (const float*)d_in[14];
    const float* b_out = (const float*)d_in[15];
    float* out = (float*)d_out;

    float* wc = (float*)d_ws;            // 64*96 floats
    float* bc = wc + ZZ * CC;            // 96 floats

    precombine_kernel<<<ZZ + 1, 128, 0, stream>>>(w_in, b_in, w_out, b_out, wc, bc);
    readout_kernel<<<BB * NPT, 128, 0, stream>>>(xs, ys, wc, bc, out);
}

// Round 3
// 9.398 us; speedup vs baseline: 1.3692x; 1.3692x over previous
//
#include <hip/hip_runtime.h>

// SoftmaxEncoder_20160576488053 — round 3
//
// Insight (round 1): the reference's cot/transformer loop only APPENDS rows
// to H; readout uses H[:, :11, :] = the initial embedding of rows 0..10.
//   out[b,p,c] = (z @ W_in + b_in) @ W_out[:, 32+c] + b_out[32+c]
//   z = [ys[b,p,:] | (p<5 ? xs[b,p,:] : 0) | zeros]   (64 active entries)
//
// Round-2 A/B showed a second (dependent) dispatch costs ~3.2 us of replay
// overhead — far more than the math. So: ONE dispatch, minimized latency:
//  - 4 independent accumulators in both dot phases (breaks the serial
//    fmaf dependency chain, 192 -> ~48 dependent FMAs)
//  - float4 z staging (16 lanes instead of 64 scalar loads)
//
// Inputs: 0 xs, 1 ys, 2 head_mask, 3 read_in_w, 4 read_in_b, 5..13 unused,
// 14 read_out_w, 15 read_out_b. Output: (64, 11, 96) float32.

#define BB    64
#define NPT   11
#define DD    32
#define EE    128
#define CC    96
#define ZZ    64
#define HALFN 5

__global__ __launch_bounds__(128) void readout_kernel(
    const float* __restrict__ xs,    // (64,256,32)
    const float* __restrict__ ys,    // (64,256,32)
    const float* __restrict__ w_in,  // (128,128)
    const float* __restrict__ b_in,  // (128)
    const float* __restrict__ w_out, // (128,128)
    const float* __restrict__ b_out, // (128)
    float* __restrict__ out)         // (64,11,96)
{
    const int b = blockIdx.x / NPT;
    const int p = blockIdx.x % NPT;
    const int t = threadIdx.x;

    __shared__ float z[ZZ];
    __shared__ float hrow[EE];

    // Stage z with float4 loads: lanes 0..7 -> ys row, lanes 8..15 -> xs row.
    if (t < 8) {
        ((float4*)z)[t] = ((const float4*)(ys + (b * 256 + p) * DD))[t];
    } else if (t < 16) {
        float4 v = make_float4(0.f, 0.f, 0.f, 0.f);
        if (p < HALFN) v = ((const float4*)(xs + (b * 256 + p) * DD))[t - 8];
        ((float4*)z)[t] = v;
    }
    __syncthreads();

    // Phase 1: hrow[t] = b_in[t] + sum_{e<64} z[e] * w_in[e,t]
    {
        float a0 = b_in[t], a1 = 0.f, a2 = 0.f, a3 = 0.f;
        #pragma unroll
        for (int e = 0; e < ZZ; e += 4) {
            a0 = fmaf(z[e + 0], w_in[(e + 0) * EE + t], a0);
            a1 = fmaf(z[e + 1], w_in[(e + 1) * EE + t], a1);
            a2 = fmaf(z[e + 2], w_in[(e + 2) * EE + t], a2);
            a3 = fmaf(z[e + 3], w_in[(e + 3) * EE + t], a3);
        }
        hrow[t] = (a0 + a1) + (a2 + a3);
    }
    __syncthreads();

    // Phase 2: out[b,p,t] = b_out[32+t] + sum_{f<128} hrow[f] * w_out[f,32+t]
    if (t < CC) {
        float a0 = b_out[DD + t], a1 = 0.f, a2 = 0.f, a3 = 0.f;
        #pragma unroll
        for (int f = 0; f < EE; f += 4) {
            a0 = fmaf(hrow[f + 0], w_out[(f + 0) * EE + DD + t], a0);
            a1 = fmaf(hrow[f + 1], w_out[(f + 1) * EE + DD + t], a1);
            a2 = fmaf(hrow[f + 2], w_out[(f + 2) * EE + DD + t], a2);
            a3 = fmaf(hrow[f + 3], w_out[(f + 3) * EE + DD + t], a3);
        }
        out[(b * NPT + p) * CC + t] = (a0 + a1) + (a2 + a3);
    }
}

extern "C" void kernel_launch(void* const* d_in, const int* in_sizes, int n_in,
                              void* d_out, int out_size, void* d_ws, size_t ws_size,
                              hipStream_t stream) {
    const float* xs    = (const float*)d_in[0];
    const float* ys    = (const float*)d_in[1];
    const float* w_in  = (const float*)d_in[3];
    const float* b_in  = (const float*)d_in[4];
    const float* w_out = (const float*)d_in[14];
    const float* b_out = (const float*)d_in[15];
    float* out = (float*)d_out;

    readout_kernel<<<BB * NPT, 128, 0, stream>>>(xs, ys, w_in, b_in, w_out, b_out, out);
}